// Round 3
// baseline (621.515 us; speedup 1.0000x reference)
//
#include <hip/hip_runtime.h>
#include <cstdint>
#include <cstddef>

#define D 128
#define NAGG 2048

// ---------------- graph build ----------------
// edge_index arrives as int32 (harness converts all integer inputs to int):
// ei[0..E-1] = src, ei[E..2E-1] = dst.

__global__ void count_kernel(const int* __restrict__ ei, int* __restrict__ counts, int E) {
  for (int e = blockIdx.x * blockDim.x + threadIdx.x; e < E; e += gridDim.x * blockDim.x) {
    int d = ei[(size_t)E + e];
    atomicAdd(&counts[d], 1);
  }
}

__global__ void dinv_kernel(const int* __restrict__ counts, float* __restrict__ dinv, int N) {
  int i = blockIdx.x * blockDim.x + threadIdx.x;
  if (i < N) dinv[i] = rsqrtf((float)counts[i] + 1.0f);
}

// single-block exclusive scan of counts -> row_ptr (and a second copy in cursor)
__global__ void scan_kernel(const int* __restrict__ counts, int* __restrict__ row_ptr,
                            int* __restrict__ cursor, int N) {
  __shared__ int part[1024];
  const int t = threadIdx.x;
  const int chunk = (N + 1023) >> 10;
  int lo = t * chunk, hi = min(lo + chunk, N);
  int s = 0;
  for (int i = lo; i < hi; i++) s += counts[i];
  part[t] = s;
  __syncthreads();
  for (int off = 1; off < 1024; off <<= 1) {
    int v = part[t];
    int u = (t >= off) ? part[t - off] : 0;
    __syncthreads();
    part[t] = v + u;
    __syncthreads();
  }
  int run = (t == 0) ? 0 : part[t - 1];
  for (int i = lo; i < hi; i++) { row_ptr[i] = run; cursor[i] = run; run += counts[i]; }
  if (t == 1023) row_ptr[N] = part[1023];
}

__global__ void fill_kernel(const int* __restrict__ ei, int* __restrict__ cursor,
                            int* __restrict__ col, int E) {
  for (int e = blockIdx.x * blockDim.x + threadIdx.x; e < E; e += gridDim.x * blockDim.x) {
    int s = ei[e];
    int d = ei[(size_t)E + e];
    int pos = atomicAdd(&cursor[d], 1);
    col[pos] = s;
  }
}

// ---------------- GEMM: out[r][c] = dinv[r] * sum_k T(A[r][k]) * W[k][c] ----------------
// T = BN+ReLU of previous layer (identity when scale==nullptr).
// M x 128 @ 128 x 128, fp32 VALU (no fp32 MFMA on CDNA4).
// block: 256 threads, tile 128 rows x 128 cols, 8x8 per-thread micro-tile, K chunked by 32.

__global__ __launch_bounds__(256) void gemm_kernel(
    const float* __restrict__ A, const float* __restrict__ Wm,
    const float* __restrict__ scale, const float* __restrict__ shift,
    const float* __restrict__ rowscale, float* __restrict__ out, int M) {
  __shared__ float At[32][132];   // [kk][row], pad 128->132 keeps b128 aligned, spreads banks
  __shared__ float Wl[32][128];   // [kk][col]
  const int tid = threadIdx.x;
  const int tr = tid >> 4;        // 0..15 -> rows tr*8..tr*8+7
  const int tc = tid & 15;        // 0..15 -> cols tc*4..+3 and tc*4+64..+67
  const int bm = blockIdx.x * 128;

  float acc[8][8];
#pragma unroll
  for (int r = 0; r < 8; r++)
#pragma unroll
    for (int c = 0; c < 8; c++) acc[r][c] = 0.f;

  for (int k0 = 0; k0 < 128; k0 += 32) {
    __syncthreads();
    // stage A^T (with fused BN+ReLU)
#pragma unroll
    for (int i = 0; i < 4; i++) {
      int idx = tid + i * 256;         // 0..1023
      int row = idx >> 3;              // 0..127
      int kk = (idx & 7) << 2;         // 0,4,...,28
      int gr = bm + row;
      float4 v = make_float4(0.f, 0.f, 0.f, 0.f);
      if (gr < M) {
        v = *(const float4*)(A + (size_t)gr * D + k0 + kk);
        if (scale) {
          int c = k0 + kk;
          v.x = fmaxf(fmaf(v.x, scale[c + 0], shift[c + 0]), 0.f);
          v.y = fmaxf(fmaf(v.y, scale[c + 1], shift[c + 1]), 0.f);
          v.z = fmaxf(fmaf(v.z, scale[c + 2], shift[c + 2]), 0.f);
          v.w = fmaxf(fmaf(v.w, scale[c + 3], shift[c + 3]), 0.f);
        }
      }
      At[kk + 0][row] = v.x; At[kk + 1][row] = v.y;
      At[kk + 2][row] = v.z; At[kk + 3][row] = v.w;
    }
    // stage W chunk
#pragma unroll
    for (int i = 0; i < 4; i++) {
      int idx = tid + i * 256;
      int kk = idx >> 5;               // 0..31
      int c4 = (idx & 31) << 2;        // 0..124
      *(float4*)&Wl[kk][c4] = *(const float4*)(Wm + (size_t)(k0 + kk) * D + c4);
    }
    __syncthreads();

#pragma unroll 4
    for (int kk = 0; kk < 32; kk++) {
      float4 alo = *(const float4*)&At[kk][tr * 8];
      float4 ahi = *(const float4*)&At[kk][tr * 8 + 4];
      float4 blo = *(const float4*)&Wl[kk][tc * 4];
      float4 bhi = *(const float4*)&Wl[kk][tc * 4 + 64];
      float a[8] = {alo.x, alo.y, alo.z, alo.w, ahi.x, ahi.y, ahi.z, ahi.w};
      float b[8] = {blo.x, blo.y, blo.z, blo.w, bhi.x, bhi.y, bhi.z, bhi.w};
#pragma unroll
      for (int r = 0; r < 8; r++)
#pragma unroll
        for (int c = 0; c < 8; c++) acc[r][c] = fmaf(a[r], b[c], acc[r][c]);
    }
  }

#pragma unroll
  for (int r = 0; r < 8; r++) {
    int gr = bm + tr * 8 + r;
    if (gr < M) {
      float dv = rowscale[gr];
      float4 o0 = make_float4(acc[r][0] * dv, acc[r][1] * dv, acc[r][2] * dv, acc[r][3] * dv);
      float4 o1 = make_float4(acc[r][4] * dv, acc[r][5] * dv, acc[r][6] * dv, acc[r][7] * dv);
      *(float4*)(out + (size_t)gr * D + tc * 4) = o0;
      *(float4*)(out + (size_t)gr * D + tc * 4 + 64) = o1;
    }
  }
}

// ---------------- aggregation: y[n] = dinv[n]*(hp[n] + sum_{s in N(n)} hp[s]) + bias ----------------
// hp is pre-scaled by dinv (GEMM epilogue). One wave per dst node; lane owns cols 2l,2l+1.
// Also emits per-block partial column sum / sumsq of y for BatchNorm.

__global__ __launch_bounds__(256) void agg_kernel(
    const float* __restrict__ hp, const int* __restrict__ row_ptr, const int* __restrict__ col,
    const float* __restrict__ dinv, const float* __restrict__ bias,
    float* __restrict__ y, float* __restrict__ pstats, int M) {
  const int tid = threadIdx.x;
  const int wave = tid >> 6;
  const int lane = tid & 63;
  const float bx = bias[lane * 2];
  const float by = bias[lane * 2 + 1];
  float sx = 0.f, sy = 0.f, qx = 0.f, qy = 0.f;

  for (int n = blockIdx.x * 4 + wave; n < M; n += gridDim.x * 4) {
    const int beg = row_ptr[n];
    const int end = row_ptr[n + 1];
    const float dn = dinv[n];
    const float2 self = *(const float2*)(hp + (size_t)n * D + lane * 2);
    float ax = self.x, ay = self.y;
#pragma unroll 4
    for (int e = beg; e < end; e++) {
      int s = col[e];
      float2 hv = *(const float2*)(hp + (size_t)s * D + lane * 2);
      ax += hv.x; ay += hv.y;
    }
    ax = fmaf(ax, dn, bx);
    ay = fmaf(ay, dn, by);
    *(float2*)(y + (size_t)n * D + lane * 2) = make_float2(ax, ay);
    sx += ax; sy += ay;
    qx = fmaf(ax, ax, qx); qy = fmaf(ay, ay, qy);
  }

  __shared__ float ps[4][128];
  ps[wave][lane * 2] = sx; ps[wave][lane * 2 + 1] = sy;
  __syncthreads();
  if (tid < 128) {
    float s = ps[0][tid] + ps[1][tid] + ps[2][tid] + ps[3][tid];
    pstats[(size_t)blockIdx.x * 256 + tid] = s;
  }
  __syncthreads();
  ps[wave][lane * 2] = qx; ps[wave][lane * 2 + 1] = qy;
  __syncthreads();
  if (tid < 128) {
    float s = ps[0][tid] + ps[1][tid] + ps[2][tid] + ps[3][tid];
    pstats[(size_t)blockIdx.x * 256 + 128 + tid] = s;
  }
}

// ---------------- BN param reduce: one block per column ----------------

__global__ void bnred_kernel(const float* __restrict__ pstats, const float* __restrict__ g,
                             const float* __restrict__ be, float* __restrict__ scale,
                             float* __restrict__ shift, float invN) {
  const int c = blockIdx.x;
  const int tid = threadIdx.x;
  float s = 0.f, q = 0.f;
  for (int b = tid; b < NAGG; b += 256) {
    s += pstats[(size_t)b * 256 + c];
    q += pstats[(size_t)b * 256 + 128 + c];
  }
  __shared__ float rs[256], rq[256];
  rs[tid] = s; rq[tid] = q;
  __syncthreads();
  for (int off = 128; off > 0; off >>= 1) {
    if (tid < off) { rs[tid] += rs[tid + off]; rq[tid] += rq[tid + off]; }
    __syncthreads();
  }
  if (tid == 0) {
    float mean = rs[0] * invN;
    float var = rq[0] * invN - mean * mean;
    float sc = g[c] * rsqrtf(var + 1e-5f);
    scale[c] = sc;
    shift[c] = be[c] - mean * sc;
  }
}

// ---------------- mean-pool of relu(bn(y)) -> per-block partials ----------------

__global__ __launch_bounds__(256) void pool_kernel(
    const float* __restrict__ y, const float* __restrict__ scale, const float* __restrict__ shift,
    float* __restrict__ ppool, int M) {
  const int tid = threadIdx.x;
  const int wave = tid >> 6;
  const int lane = tid & 63;
  const float scx = scale[lane * 2], scy = scale[lane * 2 + 1];
  const float shx = shift[lane * 2], shy = shift[lane * 2 + 1];
  float sx = 0.f, sy = 0.f;
  for (int n = blockIdx.x * 4 + wave; n < M; n += gridDim.x * 4) {
    float2 v = *(const float2*)(y + (size_t)n * D + lane * 2);
    sx += fmaxf(fmaf(v.x, scx, shx), 0.f);
    sy += fmaxf(fmaf(v.y, scy, shy), 0.f);
  }
  __shared__ float ps[4][128];
  ps[wave][lane * 2] = sx; ps[wave][lane * 2 + 1] = sy;
  __syncthreads();
  if (tid < 128) {
    float s = ps[0][tid] + ps[1][tid] + ps[2][tid] + ps[3][tid];
    ppool[(size_t)blockIdx.x * 128 + tid] = s;
  }
}

__global__ void poolred_kernel(const float* __restrict__ ppool, float* __restrict__ pooled, float invN) {
  const int c = blockIdx.x;
  const int tid = threadIdx.x;
  float s = 0.f;
  for (int b = tid; b < NAGG; b += 256) s += ppool[(size_t)b * 128 + c];
  __shared__ float rs[256];
  rs[tid] = s;
  __syncthreads();
  for (int off = 128; off > 0; off >>= 1) {
    if (tid < off) rs[tid] += rs[tid + off];
    __syncthreads();
  }
  if (tid == 0) pooled[c] = rs[0] * invN;
}

// ---------------- classifier head: [1,128] -> relu@cW1 -> [1,64] -> @cW2 -> [1,5] ----------------

__global__ void mlp_kernel(const float* __restrict__ pooled,
                           const float* __restrict__ cW1, const float* __restrict__ cb1,
                           const float* __restrict__ cW2, const float* __restrict__ cb2,
                           float* __restrict__ outp) {
  __shared__ float pl[128];
  __shared__ float h1[64];
  const int tid = threadIdx.x;
  if (tid < 128) pl[tid] = pooled[tid];
  __syncthreads();
  if (tid < 64) {
    float s = cb1[tid];
    for (int k = 0; k < 128; k++) s = fmaf(pl[k], cW1[(size_t)k * 64 + tid], s);
    h1[tid] = fmaxf(s, 0.f);
  }
  __syncthreads();
  if (tid < 5) {
    float s = cb2[tid];
    for (int k = 0; k < 64; k++) s = fmaf(h1[k], cW2[(size_t)k * 5 + tid], s);
    outp[tid] = s;
  }
}

// ---------------- launch ----------------

extern "C" void kernel_launch(void* const* d_in, const int* in_sizes, int n_in,
                              void* d_out, int out_size, void* d_ws, size_t ws_size,
                              hipStream_t stream) {
  const float* x = (const float*)d_in[0];
  const int* ei = (const int*)d_in[1];
  const float* Wm[3] = {(const float*)d_in[2], (const float*)d_in[6], (const float*)d_in[10]};
  const float* bb[3] = {(const float*)d_in[3], (const float*)d_in[7], (const float*)d_in[11]};
  const float* gg[3] = {(const float*)d_in[4], (const float*)d_in[8], (const float*)d_in[12]};
  const float* be[3] = {(const float*)d_in[5], (const float*)d_in[9], (const float*)d_in[13]};
  const float* cW1 = (const float*)d_in[14];
  const float* cb1 = (const float*)d_in[15];
  const float* cW2 = (const float*)d_in[16];
  const float* cb2 = (const float*)d_in[17];
  float* outp = (float*)d_out;

  const int N = in_sizes[0] / D;
  const int E = in_sizes[1] / 2;

  char* wsp = (char*)d_ws;
  size_t off = 0;
  auto alloc = [&](size_t bytes) -> char* {
    char* p = wsp + off;
    off += (bytes + 255) & ~(size_t)255;
    return p;
  };
  int* counts   = (int*)alloc((size_t)N * 4);
  float* dinv   = (float*)alloc((size_t)N * 4);
  int* row_ptr  = (int*)alloc((size_t)(N + 1) * 4);
  int* cursor   = (int*)alloc((size_t)N * 4);
  int* col      = (int*)alloc((size_t)E * 4);
  float* h      = (float*)alloc((size_t)N * D * 4);
  float* y      = (float*)alloc((size_t)N * D * 4);
  float* pstats = (float*)alloc((size_t)NAGG * 256 * 4);
  float* ppool  = (float*)alloc((size_t)NAGG * 128 * 4);
  float* sc     = (float*)alloc(3 * 128 * 4);
  float* sh     = (float*)alloc(3 * 128 * 4);
  float* pooled = (float*)alloc(128 * 4);
  (void)ws_size; (void)n_in; (void)out_size;

  hipMemsetAsync(counts, 0, (size_t)N * 4, stream);
  count_kernel<<<2048, 256, 0, stream>>>(ei, counts, E);
  dinv_kernel<<<(N + 255) / 256, 256, 0, stream>>>(counts, dinv, N);
  scan_kernel<<<1, 1024, 0, stream>>>(counts, row_ptr, cursor, N);
  fill_kernel<<<2048, 256, 0, stream>>>(ei, cursor, col, E);

  const int gblocks = (N + 127) / 128;
  const float invN = 1.0f / (float)N;
  for (int L = 0; L < 3; L++) {
    const float* in = (L == 0) ? x : y;
    const float* scl = (L == 0) ? nullptr : sc + (size_t)(L - 1) * 128;
    const float* shf = (L == 0) ? nullptr : sh + (size_t)(L - 1) * 128;
    gemm_kernel<<<gblocks, 256, 0, stream>>>(in, Wm[L], scl, shf, dinv, h, N);
    agg_kernel<<<NAGG, 256, 0, stream>>>(h, row_ptr, col, dinv, bb[L], y, pstats, N);
    bnred_kernel<<<128, 256, 0, stream>>>(pstats, gg[L], be[L], sc + (size_t)L * 128,
                                          sh + (size_t)L * 128, invN);
  }
  pool_kernel<<<NAGG, 256, 0, stream>>>(y, sc + 256, sh + 256, ppool, N);
  poolred_kernel<<<128, 256, 0, stream>>>(ppool, pooled, invN);
  mlp_kernel<<<1, 128, 0, stream>>>(pooled, cW1, cb1, cW2, cb2, outp);
}

// Round 4
// 513.716 us; speedup vs baseline: 1.2098x; 1.2098x over previous
//
#include <hip/hip_runtime.h>
#include <cstdint>
#include <cstddef>

#define D 128
#define NAGG 2048
#define SCAN_BLOCKS 256

// ---------------- graph build ----------------
// edge_index arrives as int32 (harness converts all integer inputs to int):
// ei[0..E-1] = src, ei[E..2E-1] = dst.

__global__ void count_kernel(const int* __restrict__ ei, int* __restrict__ counts, int E) {
  for (int e = blockIdx.x * blockDim.x + threadIdx.x; e < E; e += gridDim.x * blockDim.x) {
    int d = ei[(size_t)E + e];
    atomicAdd(&counts[d], 1);
  }
}

__global__ void dinv_kernel(const int* __restrict__ counts, float* __restrict__ dinv, int N) {
  int i = blockIdx.x * blockDim.x + threadIdx.x;
  if (i < N) dinv[i] = rsqrtf((float)counts[i] + 1.0f);
}

// ---- three-phase exclusive scan of counts -> row_ptr (+ copy in cursor) ----
// R3: single-block scan_kernel was 111 us (0.14% occupancy, top dispatch).

__global__ __launch_bounds__(256) void scan1_kernel(const int* __restrict__ counts,
                                                    int* __restrict__ blocksums, int N) {
  __shared__ int red[256];
  const int b = blockIdx.x, t = threadIdx.x;
  const int chunk = (N + SCAN_BLOCKS - 1) / SCAN_BLOCKS;
  const int lo = b * chunk, hi = min(lo + chunk, N);
  int s = 0;
  for (int i = lo + t; i < hi; i += 256) s += counts[i];
  red[t] = s;
  __syncthreads();
  for (int off = 128; off > 0; off >>= 1) {
    if (t < off) red[t] += red[t + off];
    __syncthreads();
  }
  if (t == 0) blocksums[b] = red[0];
}

__global__ __launch_bounds__(256) void scan2_kernel(int* __restrict__ blocksums) {
  __shared__ int part[256];
  const int t = threadIdx.x;
  part[t] = blocksums[t];
  __syncthreads();
  for (int off = 1; off < 256; off <<= 1) {
    int v = part[t];
    int u = (t >= off) ? part[t - off] : 0;
    __syncthreads();
    part[t] = v + u;
    __syncthreads();
  }
  blocksums[t] = (t == 0) ? 0 : part[t - 1];  // exclusive
}

__global__ __launch_bounds__(256) void scan3_kernel(const int* __restrict__ counts,
                                                    const int* __restrict__ blocksums,
                                                    int* __restrict__ row_ptr,
                                                    int* __restrict__ cursor, int N) {
  __shared__ int tsum[256];
  const int b = blockIdx.x, t = threadIdx.x;
  const int chunk = (N + SCAN_BLOCKS - 1) / SCAN_BLOCKS;
  const int lo = b * chunk, hi = min(lo + chunk, N);
  const int tchunk = (chunk + 255) >> 8;
  const int tlo = lo + t * tchunk, thi = min(tlo + tchunk, hi);
  int s = 0;
  for (int i = tlo; i < thi; i++) s += counts[i];
  tsum[t] = s;
  __syncthreads();
  for (int off = 1; off < 256; off <<= 1) {
    int v = tsum[t];
    int u = (t >= off) ? tsum[t - off] : 0;
    __syncthreads();
    tsum[t] = v + u;
    __syncthreads();
  }
  int run = blocksums[b] + ((t == 0) ? 0 : tsum[t - 1]);
  for (int i = tlo; i < thi; i++) { row_ptr[i] = run; cursor[i] = run; run += counts[i]; }
  if (b == SCAN_BLOCKS - 1 && t == 255) row_ptr[N] = blocksums[b] + tsum[255];
}

__global__ void fill_kernel(const int* __restrict__ ei, int* __restrict__ cursor,
                            int* __restrict__ col, int E) {
  for (int e = blockIdx.x * blockDim.x + threadIdx.x; e < E; e += gridDim.x * blockDim.x) {
    int s = ei[e];
    int d = ei[(size_t)E + e];
    int pos = atomicAdd(&cursor[d], 1);
    col[pos] = s;
  }
}

// ---------------- GEMM: out[r][c] = dinv[r] * sum_k T(A[r][k]) * W[k][c] ----------------
// T = BN+ReLU of previous layer (identity when scale==nullptr).
// M x 128 @ 128 x 128, fp32 VALU (no fp32 MFMA on CDNA4).
// block: 256 threads, tile 128 rows x 128 cols, 8x8 per-thread micro-tile, K chunked by 32.

__global__ __launch_bounds__(256) void gemm_kernel(
    const float* __restrict__ A, const float* __restrict__ Wm,
    const float* __restrict__ scale, const float* __restrict__ shift,
    const float* __restrict__ rowscale, float* __restrict__ out, int M) {
  __shared__ float At[32][132];   // [kk][row], pad 128->132 keeps b128 aligned, spreads banks
  __shared__ float Wl[32][128];   // [kk][col]
  const int tid = threadIdx.x;
  const int tr = tid >> 4;        // 0..15 -> rows tr*8..tr*8+7
  const int tc = tid & 15;        // 0..15 -> cols tc*4..+3 and tc*4+64..+67
  const int bm = blockIdx.x * 128;

  float acc[8][8];
#pragma unroll
  for (int r = 0; r < 8; r++)
#pragma unroll
    for (int c = 0; c < 8; c++) acc[r][c] = 0.f;

  for (int k0 = 0; k0 < 128; k0 += 32) {
    __syncthreads();
    // stage A^T (with fused BN+ReLU)
#pragma unroll
    for (int i = 0; i < 4; i++) {
      int idx = tid + i * 256;         // 0..1023
      int row = idx >> 3;              // 0..127
      int kk = (idx & 7) << 2;         // 0,4,...,28
      int gr = bm + row;
      float4 v = make_float4(0.f, 0.f, 0.f, 0.f);
      if (gr < M) {
        v = *(const float4*)(A + (size_t)gr * D + k0 + kk);
        if (scale) {
          int c = k0 + kk;
          v.x = fmaxf(fmaf(v.x, scale[c + 0], shift[c + 0]), 0.f);
          v.y = fmaxf(fmaf(v.y, scale[c + 1], shift[c + 1]), 0.f);
          v.z = fmaxf(fmaf(v.z, scale[c + 2], shift[c + 2]), 0.f);
          v.w = fmaxf(fmaf(v.w, scale[c + 3], shift[c + 3]), 0.f);
        }
      }
      At[kk + 0][row] = v.x; At[kk + 1][row] = v.y;
      At[kk + 2][row] = v.z; At[kk + 3][row] = v.w;
    }
    // stage W chunk
#pragma unroll
    for (int i = 0; i < 4; i++) {
      int idx = tid + i * 256;
      int kk = idx >> 5;               // 0..31
      int c4 = (idx & 31) << 2;        // 0..124
      *(float4*)&Wl[kk][c4] = *(const float4*)(Wm + (size_t)(k0 + kk) * D + c4);
    }
    __syncthreads();

#pragma unroll 4
    for (int kk = 0; kk < 32; kk++) {
      float4 alo = *(const float4*)&At[kk][tr * 8];
      float4 ahi = *(const float4*)&At[kk][tr * 8 + 4];
      float4 blo = *(const float4*)&Wl[kk][tc * 4];
      float4 bhi = *(const float4*)&Wl[kk][tc * 4 + 64];
      float a[8] = {alo.x, alo.y, alo.z, alo.w, ahi.x, ahi.y, ahi.z, ahi.w};
      float b[8] = {blo.x, blo.y, blo.z, blo.w, bhi.x, bhi.y, bhi.z, bhi.w};
#pragma unroll
      for (int r = 0; r < 8; r++)
#pragma unroll
        for (int c = 0; c < 8; c++) acc[r][c] = fmaf(a[r], b[c], acc[r][c]);
    }
  }

#pragma unroll
  for (int r = 0; r < 8; r++) {
    int gr = bm + tr * 8 + r;
    if (gr < M) {
      float dv = rowscale[gr];
      float4 o0 = make_float4(acc[r][0] * dv, acc[r][1] * dv, acc[r][2] * dv, acc[r][3] * dv);
      float4 o1 = make_float4(acc[r][4] * dv, acc[r][5] * dv, acc[r][6] * dv, acc[r][7] * dv);
      *(float4*)(out + (size_t)gr * D + tc * 4) = o0;
      *(float4*)(out + (size_t)gr * D + tc * 4 + 64) = o1;
    }
  }
}

// ---------------- aggregation: y[n] = dinv[n]*(hp[n] + sum_{s in N(n)} hp[s]) + bias ----------------
// hp is pre-scaled by dinv (GEMM epilogue). One wave per dst node; lane owns cols 2l,2l+1.
// Also emits per-block partial column sum / sumsq of y for BatchNorm.

__global__ __launch_bounds__(256) void agg_kernel(
    const float* __restrict__ hp, const int* __restrict__ row_ptr, const int* __restrict__ col,
    const float* __restrict__ dinv, const float* __restrict__ bias,
    float* __restrict__ y, float* __restrict__ pstats, int M) {
  const int tid = threadIdx.x;
  const int wave = tid >> 6;
  const int lane = tid & 63;
  const float bx = bias[lane * 2];
  const float by = bias[lane * 2 + 1];
  float sx = 0.f, sy = 0.f, qx = 0.f, qy = 0.f;

  for (int n = blockIdx.x * 4 + wave; n < M; n += gridDim.x * 4) {
    const int beg = row_ptr[n];
    const int end = row_ptr[n + 1];
    const float dn = dinv[n];
    const float2 self = *(const float2*)(hp + (size_t)n * D + lane * 2);
    float ax = self.x, ay = self.y;
#pragma unroll 4
    for (int e = beg; e < end; e++) {
      int s = col[e];
      float2 hv = *(const float2*)(hp + (size_t)s * D + lane * 2);
      ax += hv.x; ay += hv.y;
    }
    ax = fmaf(ax, dn, bx);
    ay = fmaf(ay, dn, by);
    *(float2*)(y + (size_t)n * D + lane * 2) = make_float2(ax, ay);
    sx += ax; sy += ay;
    qx = fmaf(ax, ax, qx); qy = fmaf(ay, ay, qy);
  }

  __shared__ float ps[4][128];
  ps[wave][lane * 2] = sx; ps[wave][lane * 2 + 1] = sy;
  __syncthreads();
  if (tid < 128) {
    float s = ps[0][tid] + ps[1][tid] + ps[2][tid] + ps[3][tid];
    pstats[(size_t)blockIdx.x * 256 + tid] = s;
  }
  __syncthreads();
  ps[wave][lane * 2] = qx; ps[wave][lane * 2 + 1] = qy;
  __syncthreads();
  if (tid < 128) {
    float s = ps[0][tid] + ps[1][tid] + ps[2][tid] + ps[3][tid];
    pstats[(size_t)blockIdx.x * 256 + 128 + tid] = s;
  }
}

// ---------------- BN param reduce: one block per column ----------------

__global__ void bnred_kernel(const float* __restrict__ pstats, const float* __restrict__ g,
                             const float* __restrict__ be, float* __restrict__ scale,
                             float* __restrict__ shift, float invN) {
  const int c = blockIdx.x;
  const int tid = threadIdx.x;
  float s = 0.f, q = 0.f;
  for (int b = tid; b < NAGG; b += 256) {
    s += pstats[(size_t)b * 256 + c];
    q += pstats[(size_t)b * 256 + 128 + c];
  }
  __shared__ float rs[256], rq[256];
  rs[tid] = s; rq[tid] = q;
  __syncthreads();
  for (int off = 128; off > 0; off >>= 1) {
    if (tid < off) { rs[tid] += rs[tid + off]; rq[tid] += rq[tid + off]; }
    __syncthreads();
  }
  if (tid == 0) {
    float mean = rs[0] * invN;
    float var = rq[0] * invN - mean * mean;
    float sc = g[c] * rsqrtf(var + 1e-5f);
    scale[c] = sc;
    shift[c] = be[c] - mean * sc;
  }
}

// ---------------- mean-pool of relu(bn(y)) -> per-block partials ----------------

__global__ __launch_bounds__(256) void pool_kernel(
    const float* __restrict__ y, const float* __restrict__ scale, const float* __restrict__ shift,
    float* __restrict__ ppool, int M) {
  const int tid = threadIdx.x;
  const int wave = tid >> 6;
  const int lane = tid & 63;
  const float scx = scale[lane * 2], scy = scale[lane * 2 + 1];
  const float shx = shift[lane * 2], shy = shift[lane * 2 + 1];
  float sx = 0.f, sy = 0.f;
  for (int n = blockIdx.x * 4 + wave; n < M; n += gridDim.x * 4) {
    float2 v = *(const float2*)(y + (size_t)n * D + lane * 2);
    sx += fmaxf(fmaf(v.x, scx, shx), 0.f);
    sy += fmaxf(fmaf(v.y, scy, shy), 0.f);
  }
  __shared__ float ps[4][128];
  ps[wave][lane * 2] = sx; ps[wave][lane * 2 + 1] = sy;
  __syncthreads();
  if (tid < 128) {
    float s = ps[0][tid] + ps[1][tid] + ps[2][tid] + ps[3][tid];
    ppool[(size_t)blockIdx.x * 128 + tid] = s;
  }
}

__global__ void poolred_kernel(const float* __restrict__ ppool, float* __restrict__ pooled, float invN) {
  const int c = blockIdx.x;
  const int tid = threadIdx.x;
  float s = 0.f;
  for (int b = tid; b < NAGG; b += 256) s += ppool[(size_t)b * 128 + c];
  __shared__ float rs[256];
  rs[tid] = s;
  __syncthreads();
  for (int off = 128; off > 0; off >>= 1) {
    if (tid < off) rs[tid] += rs[tid + off];
    __syncthreads();
  }
  if (tid == 0) pooled[c] = rs[0] * invN;
}

// ---------------- classifier head: [1,128] -> relu@cW1 -> [1,64] -> @cW2 -> [1,5] ----------------

__global__ void mlp_kernel(const float* __restrict__ pooled,
                           const float* __restrict__ cW1, const float* __restrict__ cb1,
                           const float* __restrict__ cW2, const float* __restrict__ cb2,
                           float* __restrict__ outp) {
  __shared__ float pl[128];
  __shared__ float h1[64];
  const int tid = threadIdx.x;
  if (tid < 128) pl[tid] = pooled[tid];
  __syncthreads();
  if (tid < 64) {
    float s = cb1[tid];
    for (int k = 0; k < 128; k++) s = fmaf(pl[k], cW1[(size_t)k * 64 + tid], s);
    h1[tid] = fmaxf(s, 0.f);
  }
  __syncthreads();
  if (tid < 5) {
    float s = cb2[tid];
    for (int k = 0; k < 64; k++) s = fmaf(h1[k], cW2[(size_t)k * 5 + tid], s);
    outp[tid] = s;
  }
}

// ---------------- launch ----------------

extern "C" void kernel_launch(void* const* d_in, const int* in_sizes, int n_in,
                              void* d_out, int out_size, void* d_ws, size_t ws_size,
                              hipStream_t stream) {
  const float* x = (const float*)d_in[0];
  const int* ei = (const int*)d_in[1];
  const float* Wm[3] = {(const float*)d_in[2], (const float*)d_in[6], (const float*)d_in[10]};
  const float* bb[3] = {(const float*)d_in[3], (const float*)d_in[7], (const float*)d_in[11]};
  const float* gg[3] = {(const float*)d_in[4], (const float*)d_in[8], (const float*)d_in[12]};
  const float* be[3] = {(const float*)d_in[5], (const float*)d_in[9], (const float*)d_in[13]};
  const float* cW1 = (const float*)d_in[14];
  const float* cb1 = (const float*)d_in[15];
  const float* cW2 = (const float*)d_in[16];
  const float* cb2 = (const float*)d_in[17];
  float* outp = (float*)d_out;

  const int N = in_sizes[0] / D;
  const int E = in_sizes[1] / 2;

  char* wsp = (char*)d_ws;
  size_t off = 0;
  auto alloc = [&](size_t bytes) -> char* {
    char* p = wsp + off;
    off += (bytes + 255) & ~(size_t)255;
    return p;
  };
  int* counts   = (int*)alloc((size_t)N * 4);
  float* dinv   = (float*)alloc((size_t)N * 4);
  int* row_ptr  = (int*)alloc((size_t)(N + 1) * 4);
  int* cursor   = (int*)alloc((size_t)N * 4);
  int* col      = (int*)alloc((size_t)E * 4);
  float* h      = (float*)alloc((size_t)N * D * 4);
  float* y      = (float*)alloc((size_t)N * D * 4);
  float* pstats = (float*)alloc((size_t)NAGG * 256 * 4);
  float* ppool  = (float*)alloc((size_t)NAGG * 128 * 4);
  float* sc     = (float*)alloc(3 * 128 * 4);
  float* sh     = (float*)alloc(3 * 128 * 4);
  float* pooled = (float*)alloc(128 * 4);
  int* blocksums= (int*)alloc(SCAN_BLOCKS * 4);
  (void)ws_size; (void)n_in; (void)out_size;

  hipMemsetAsync(counts, 0, (size_t)N * 4, stream);
  count_kernel<<<2048, 256, 0, stream>>>(ei, counts, E);
  dinv_kernel<<<(N + 255) / 256, 256, 0, stream>>>(counts, dinv, N);
  scan1_kernel<<<SCAN_BLOCKS, 256, 0, stream>>>(counts, blocksums, N);
  scan2_kernel<<<1, 256, 0, stream>>>(blocksums);
  scan3_kernel<<<SCAN_BLOCKS, 256, 0, stream>>>(counts, blocksums, row_ptr, cursor, N);
  fill_kernel<<<2048, 256, 0, stream>>>(ei, cursor, col, E);

  const int gblocks = (N + 127) / 128;
  const float invN = 1.0f / (float)N;
  for (int L = 0; L < 3; L++) {
    const float* in = (L == 0) ? x : y;
    const float* scl = (L == 0) ? nullptr : sc + (size_t)(L - 1) * 128;
    const float* shf = (L == 0) ? nullptr : sh + (size_t)(L - 1) * 128;
    gemm_kernel<<<gblocks, 256, 0, stream>>>(in, Wm[L], scl, shf, dinv, h, N);
    agg_kernel<<<NAGG, 256, 0, stream>>>(h, row_ptr, col, dinv, bb[L], y, pstats, N);
    bnred_kernel<<<128, 256, 0, stream>>>(pstats, gg[L], be[L], sc + (size_t)L * 128,
                                          sh + (size_t)L * 128, invN);
  }
  pool_kernel<<<NAGG, 256, 0, stream>>>(y, sc + 256, sh + 256, ppool, N);
  poolred_kernel<<<128, 256, 0, stream>>>(ppool, pooled, invN);
  mlp_kernel<<<1, 128, 0, stream>>>(pooled, cW1, cb1, cW2, cb2, outp);
}

// Round 5
// 437.684 us; speedup vs baseline: 1.4200x; 1.1737x over previous
//
#include <hip/hip_runtime.h>
#include <hip/hip_fp16.h>
#include <cstdint>
#include <cstddef>

#define D 128
#define NAGG 2048
#define SCAN_BLOCKS 256

// ---------------- graph build ----------------
// edge_index arrives as int32: ei[0..E-1] = src, ei[E..2E-1] = dst.

__global__ void count_kernel(const int* __restrict__ ei, int* __restrict__ counts, int E) {
  for (int e = blockIdx.x * blockDim.x + threadIdx.x; e < E; e += gridDim.x * blockDim.x) {
    int d = ei[(size_t)E + e];
    atomicAdd(&counts[d], 1);
  }
}

// ---- three-phase exclusive scan of counts -> row_ptr (+ cursor copy, + dinv) ----
// R3: single-block scan was 111 us (0.14% occupancy). R4: 3-phase fixed it.

__global__ __launch_bounds__(256) void scan1_kernel(const int* __restrict__ counts,
                                                    int* __restrict__ blocksums, int N) {
  __shared__ int red[256];
  const int b = blockIdx.x, t = threadIdx.x;
  const int chunk = (N + SCAN_BLOCKS - 1) / SCAN_BLOCKS;
  const int lo = b * chunk, hi = min(lo + chunk, N);
  int s = 0;
  for (int i = lo + t; i < hi; i += 256) s += counts[i];
  red[t] = s;
  __syncthreads();
  for (int off = 128; off > 0; off >>= 1) {
    if (t < off) red[t] += red[t + off];
    __syncthreads();
  }
  if (t == 0) blocksums[b] = red[0];
}

__global__ __launch_bounds__(256) void scan2_kernel(int* __restrict__ blocksums) {
  __shared__ int part[256];
  const int t = threadIdx.x;
  part[t] = blocksums[t];
  __syncthreads();
  for (int off = 1; off < 256; off <<= 1) {
    int v = part[t];
    int u = (t >= off) ? part[t - off] : 0;
    __syncthreads();
    part[t] = v + u;
    __syncthreads();
  }
  blocksums[t] = (t == 0) ? 0 : part[t - 1];  // exclusive
}

__global__ __launch_bounds__(256) void scan3_kernel(const int* __restrict__ counts,
                                                    const int* __restrict__ blocksums,
                                                    int* __restrict__ row_ptr,
                                                    int* __restrict__ cursor,
                                                    float* __restrict__ dinv, int N) {
  __shared__ int tsum[256];
  const int b = blockIdx.x, t = threadIdx.x;
  const int chunk = (N + SCAN_BLOCKS - 1) / SCAN_BLOCKS;
  const int lo = b * chunk, hi = min(lo + chunk, N);
  const int tchunk = (chunk + 255) >> 8;
  const int tlo = lo + t * tchunk, thi = min(tlo + tchunk, hi);
  int s = 0;
  for (int i = tlo; i < thi; i++) s += counts[i];
  tsum[t] = s;
  __syncthreads();
  for (int off = 1; off < 256; off <<= 1) {
    int v = tsum[t];
    int u = (t >= off) ? tsum[t - off] : 0;
    __syncthreads();
    tsum[t] = v + u;
    __syncthreads();
  }
  int run = blocksums[b] + ((t == 0) ? 0 : tsum[t - 1]);
  for (int i = tlo; i < thi; i++) {
    int c = counts[i];
    row_ptr[i] = run; cursor[i] = run; run += c;
    dinv[i] = rsqrtf((float)c + 1.0f);
  }
  if (b == SCAN_BLOCKS - 1 && t == 255) row_ptr[N] = blocksums[b] + tsum[255];
}

__global__ void fill_kernel(const int* __restrict__ ei, int* __restrict__ cursor,
                            int* __restrict__ col, int E) {
  for (int e = blockIdx.x * blockDim.x + threadIdx.x; e < E; e += gridDim.x * blockDim.x) {
    int s = ei[e];
    int d = ei[(size_t)E + e];
    int pos = atomicAdd(&cursor[d], 1);
    col[pos] = s;
  }
}

// ---------------- GEMM: hp16[r][c] = (half) dinv[r] * sum_k T(A[r][k]) * W[k][c] ----------------
// T = BN+ReLU of previous layer (identity when scale==nullptr). fp32 VALU math,
// fp16 output (R4: agg is L2-miss-BW bound at 187MB/dispatch; halve row bytes).

__global__ __launch_bounds__(256) void gemm_kernel(
    const float* __restrict__ A, const float* __restrict__ Wm,
    const float* __restrict__ scale, const float* __restrict__ shift,
    const float* __restrict__ rowscale, __half* __restrict__ out, int M) {
  __shared__ float At[32][132];   // [kk][row], pad 128->132
  __shared__ float Wl[32][128];   // [kk][col]
  const int tid = threadIdx.x;
  const int tr = tid >> 4;        // 0..15 -> rows tr*8..tr*8+7
  const int tc = tid & 15;        // 0..15 -> cols tc*4..+3 and tc*4+64..+67
  const int bm = blockIdx.x * 128;

  float acc[8][8];
#pragma unroll
  for (int r = 0; r < 8; r++)
#pragma unroll
    for (int c = 0; c < 8; c++) acc[r][c] = 0.f;

  for (int k0 = 0; k0 < 128; k0 += 32) {
    __syncthreads();
#pragma unroll
    for (int i = 0; i < 4; i++) {
      int idx = tid + i * 256;
      int row = idx >> 3;
      int kk = (idx & 7) << 2;
      int gr = bm + row;
      float4 v = make_float4(0.f, 0.f, 0.f, 0.f);
      if (gr < M) {
        v = *(const float4*)(A + (size_t)gr * D + k0 + kk);
        if (scale) {
          int c = k0 + kk;
          v.x = fmaxf(fmaf(v.x, scale[c + 0], shift[c + 0]), 0.f);
          v.y = fmaxf(fmaf(v.y, scale[c + 1], shift[c + 1]), 0.f);
          v.z = fmaxf(fmaf(v.z, scale[c + 2], shift[c + 2]), 0.f);
          v.w = fmaxf(fmaf(v.w, scale[c + 3], shift[c + 3]), 0.f);
        }
      }
      At[kk + 0][row] = v.x; At[kk + 1][row] = v.y;
      At[kk + 2][row] = v.z; At[kk + 3][row] = v.w;
    }
#pragma unroll
    for (int i = 0; i < 4; i++) {
      int idx = tid + i * 256;
      int kk = idx >> 5;
      int c4 = (idx & 31) << 2;
      *(float4*)&Wl[kk][c4] = *(const float4*)(Wm + (size_t)(k0 + kk) * D + c4);
    }
    __syncthreads();

#pragma unroll 4
    for (int kk = 0; kk < 32; kk++) {
      float4 alo = *(const float4*)&At[kk][tr * 8];
      float4 ahi = *(const float4*)&At[kk][tr * 8 + 4];
      float4 blo = *(const float4*)&Wl[kk][tc * 4];
      float4 bhi = *(const float4*)&Wl[kk][tc * 4 + 64];
      float a[8] = {alo.x, alo.y, alo.z, alo.w, ahi.x, ahi.y, ahi.z, ahi.w};
      float b[8] = {blo.x, blo.y, blo.z, blo.w, bhi.x, bhi.y, bhi.z, bhi.w};
#pragma unroll
      for (int r = 0; r < 8; r++)
#pragma unroll
        for (int c = 0; c < 8; c++) acc[r][c] = fmaf(a[r], b[c], acc[r][c]);
    }
  }

#pragma unroll
  for (int r = 0; r < 8; r++) {
    int gr = bm + tr * 8 + r;
    if (gr < M) {
      float dv = rowscale[gr];
      __half2 h0 = __floats2half2_rn(acc[r][0] * dv, acc[r][1] * dv);
      __half2 h1 = __floats2half2_rn(acc[r][2] * dv, acc[r][3] * dv);
      __half2 h2 = __floats2half2_rn(acc[r][4] * dv, acc[r][5] * dv);
      __half2 h3 = __floats2half2_rn(acc[r][6] * dv, acc[r][7] * dv);
      __half2* p0 = (__half2*)(out + (size_t)gr * D + tc * 4);
      __half2* p1 = (__half2*)(out + (size_t)gr * D + tc * 4 + 64);
      p0[0] = h0; p0[1] = h1;
      p1[0] = h2; p1[1] = h3;
    }
  }
}

// ---------------- aggregation: y[n] = dinv[n]*(hp[n] + sum_{s in N(n)} hp[s]) + bias ----------------
// hp is fp16, pre-scaled by dinv. One wave per dst node; lane owns cols 2l,2l+1 (one half2).
// fp32 accumulate. Emits per-block partial column sum / sumsq of y for BatchNorm.

__global__ __launch_bounds__(256) void agg_kernel(
    const __half* __restrict__ hp, const int* __restrict__ row_ptr, const int* __restrict__ col,
    const float* __restrict__ dinv, const float* __restrict__ bias,
    float* __restrict__ y, float* __restrict__ pstats, int M) {
  const int tid = threadIdx.x;
  const int wave = tid >> 6;
  const int lane = tid & 63;
  const float bx = bias[lane * 2];
  const float by = bias[lane * 2 + 1];
  float sx = 0.f, sy = 0.f, qx = 0.f, qy = 0.f;

  for (int n = blockIdx.x * 4 + wave; n < M; n += gridDim.x * 4) {
    const int beg = row_ptr[n];
    const int end = row_ptr[n + 1];
    const float dn = dinv[n];
    float2 self = __half22float2(*(const __half2*)(hp + (size_t)n * D + lane * 2));
    float ax = self.x, ay = self.y;
#pragma unroll 4
    for (int e = beg; e < end; e++) {
      int s = col[e];
      float2 hv = __half22float2(*(const __half2*)(hp + (size_t)s * D + lane * 2));
      ax += hv.x; ay += hv.y;
    }
    ax = fmaf(ax, dn, bx);
    ay = fmaf(ay, dn, by);
    *(float2*)(y + (size_t)n * D + lane * 2) = make_float2(ax, ay);
    sx += ax; sy += ay;
    qx = fmaf(ax, ax, qx); qy = fmaf(ay, ay, qy);
  }

  __shared__ float ps[4][128];
  ps[wave][lane * 2] = sx; ps[wave][lane * 2 + 1] = sy;
  __syncthreads();
  if (tid < 128) {
    float s = ps[0][tid] + ps[1][tid] + ps[2][tid] + ps[3][tid];
    pstats[(size_t)blockIdx.x * 256 + tid] = s;
  }
  __syncthreads();
  ps[wave][lane * 2] = qx; ps[wave][lane * 2 + 1] = qy;
  __syncthreads();
  if (tid < 128) {
    float s = ps[0][tid] + ps[1][tid] + ps[2][tid] + ps[3][tid];
    pstats[(size_t)blockIdx.x * 256 + 128 + tid] = s;
  }
}

// ---------------- BN param reduce: one block per column ----------------

__global__ void bnred_kernel(const float* __restrict__ pstats, const float* __restrict__ g,
                             const float* __restrict__ be, float* __restrict__ scale,
                             float* __restrict__ shift, float invN) {
  const int c = blockIdx.x;
  const int tid = threadIdx.x;
  float s = 0.f, q = 0.f;
  for (int b = tid; b < NAGG; b += 256) {
    s += pstats[(size_t)b * 256 + c];
    q += pstats[(size_t)b * 256 + 128 + c];
  }
  __shared__ float rs[256], rq[256];
  rs[tid] = s; rq[tid] = q;
  __syncthreads();
  for (int off = 128; off > 0; off >>= 1) {
    if (tid < off) { rs[tid] += rs[tid + off]; rq[tid] += rq[tid + off]; }
    __syncthreads();
  }
  if (tid == 0) {
    float mean = rs[0] * invN;
    float var = rq[0] * invN - mean * mean;
    float sc = g[c] * rsqrtf(var + 1e-5f);
    scale[c] = sc;
    shift[c] = be[c] - mean * sc;
  }
}

// ---------------- mean-pool of relu(bn(y)) -> per-block partials ----------------

__global__ __launch_bounds__(256) void pool_kernel(
    const float* __restrict__ y, const float* __restrict__ scale, const float* __restrict__ shift,
    float* __restrict__ ppool, int M) {
  const int tid = threadIdx.x;
  const int wave = tid >> 6;
  const int lane = tid & 63;
  const float scx = scale[lane * 2], scy = scale[lane * 2 + 1];
  const float shx = shift[lane * 2], shy = shift[lane * 2 + 1];
  float sx = 0.f, sy = 0.f;
  for (int n = blockIdx.x * 4 + wave; n < M; n += gridDim.x * 4) {
    float2 v = *(const float2*)(y + (size_t)n * D + lane * 2);
    sx += fmaxf(fmaf(v.x, scx, shx), 0.f);
    sy += fmaxf(fmaf(v.y, scy, shy), 0.f);
  }
  __shared__ float ps[4][128];
  ps[wave][lane * 2] = sx; ps[wave][lane * 2 + 1] = sy;
  __syncthreads();
  if (tid < 128) {
    float s = ps[0][tid] + ps[1][tid] + ps[2][tid] + ps[3][tid];
    ppool[(size_t)blockIdx.x * 128 + tid] = s;
  }
}

__global__ void poolred_kernel(const float* __restrict__ ppool, float* __restrict__ pooled, float invN) {
  const int c = blockIdx.x;
  const int tid = threadIdx.x;
  float s = 0.f;
  for (int b = tid; b < NAGG; b += 256) s += ppool[(size_t)b * 128 + c];
  __shared__ float rs[256];
  rs[tid] = s;
  __syncthreads();
  for (int off = 128; off > 0; off >>= 1) {
    if (tid < off) rs[tid] += rs[tid + off];
    __syncthreads();
  }
  if (tid == 0) pooled[c] = rs[0] * invN;
}

// ---------------- classifier head ----------------

__global__ void mlp_kernel(const float* __restrict__ pooled,
                           const float* __restrict__ cW1, const float* __restrict__ cb1,
                           const float* __restrict__ cW2, const float* __restrict__ cb2,
                           float* __restrict__ outp) {
  __shared__ float pl[128];
  __shared__ float h1[64];
  const int tid = threadIdx.x;
  if (tid < 128) pl[tid] = pooled[tid];
  __syncthreads();
  if (tid < 64) {
    float s = cb1[tid];
    for (int k = 0; k < 128; k++) s = fmaf(pl[k], cW1[(size_t)k * 64 + tid], s);
    h1[tid] = fmaxf(s, 0.f);
  }
  __syncthreads();
  if (tid < 5) {
    float s = cb2[tid];
    for (int k = 0; k < 64; k++) s = fmaf(h1[k], cW2[(size_t)k * 5 + tid], s);
    outp[tid] = s;
  }
}

// ---------------- launch ----------------

extern "C" void kernel_launch(void* const* d_in, const int* in_sizes, int n_in,
                              void* d_out, int out_size, void* d_ws, size_t ws_size,
                              hipStream_t stream) {
  const float* x = (const float*)d_in[0];
  const int* ei = (const int*)d_in[1];
  const float* Wm[3] = {(const float*)d_in[2], (const float*)d_in[6], (const float*)d_in[10]};
  const float* bb[3] = {(const float*)d_in[3], (const float*)d_in[7], (const float*)d_in[11]};
  const float* gg[3] = {(const float*)d_in[4], (const float*)d_in[8], (const float*)d_in[12]};
  const float* be[3] = {(const float*)d_in[5], (const float*)d_in[9], (const float*)d_in[13]};
  const float* cW1 = (const float*)d_in[14];
  const float* cb1 = (const float*)d_in[15];
  const float* cW2 = (const float*)d_in[16];
  const float* cb2 = (const float*)d_in[17];
  float* outp = (float*)d_out;

  const int N = in_sizes[0] / D;
  const int E = in_sizes[1] / 2;

  char* wsp = (char*)d_ws;
  size_t off = 0;
  auto alloc = [&](size_t bytes) -> char* {
    char* p = wsp + off;
    off += (bytes + 255) & ~(size_t)255;
    return p;
  };
  int* counts   = (int*)alloc((size_t)N * 4);
  float* dinv   = (float*)alloc((size_t)N * 4);
  int* row_ptr  = (int*)alloc((size_t)(N + 1) * 4);
  int* cursor   = (int*)alloc((size_t)N * 4);
  int* col      = (int*)alloc((size_t)E * 4);
  __half* h     = (__half*)alloc((size_t)N * D * 2);
  float* y      = (float*)alloc((size_t)N * D * 4);
  float* pstats = (float*)alloc((size_t)NAGG * 256 * 4);
  float* ppool  = (float*)alloc((size_t)NAGG * 128 * 4);
  float* sc     = (float*)alloc(3 * 128 * 4);
  float* sh     = (float*)alloc(3 * 128 * 4);
  float* pooled = (float*)alloc(128 * 4);
  int* blocksums= (int*)alloc(SCAN_BLOCKS * 4);
  (void)ws_size; (void)n_in; (void)out_size;

  hipMemsetAsync(counts, 0, (size_t)N * 4, stream);
  count_kernel<<<2048, 256, 0, stream>>>(ei, counts, E);
  scan1_kernel<<<SCAN_BLOCKS, 256, 0, stream>>>(counts, blocksums, N);
  scan2_kernel<<<1, 256, 0, stream>>>(blocksums);
  scan3_kernel<<<SCAN_BLOCKS, 256, 0, stream>>>(counts, blocksums, row_ptr, cursor, dinv, N);
  fill_kernel<<<2048, 256, 0, stream>>>(ei, cursor, col, E);

  const int gblocks = (N + 127) / 128;
  const float invN = 1.0f / (float)N;
  for (int L = 0; L < 3; L++) {
    const float* in = (L == 0) ? x : y;
    const float* scl = (L == 0) ? nullptr : sc + (size_t)(L - 1) * 128;
    const float* shf = (L == 0) ? nullptr : sh + (size_t)(L - 1) * 128;
    gemm_kernel<<<gblocks, 256, 0, stream>>>(in, Wm[L], scl, shf, dinv, h, N);
    agg_kernel<<<NAGG, 256, 0, stream>>>(h, row_ptr, col, dinv, bb[L], y, pstats, N);
    bnred_kernel<<<128, 256, 0, stream>>>(pstats, gg[L], be[L], sc + (size_t)L * 128,
                                          sh + (size_t)L * 128, invN);
  }
  pool_kernel<<<NAGG, 256, 0, stream>>>(y, sc + 256, sh + 256, ppool, N);
  poolred_kernel<<<128, 256, 0, stream>>>(ppool, pooled, invN);
  mlp_kernel<<<1, 128, 0, stream>>>(pooled, cW1, cb1, cW2, cb2, outp);
}